// Round 1
// 232.786 us; speedup vs baseline: 1.1015x; 1.1015x over previous
//
#include <hip/hip_runtime.h>

// MHA: D_MODEL=1024, D_K=64, H=16, N=2, T=2048. fp32 I/O, bf16 MFMA internals.
// R12: flash_attn pipelined. R9/R11 flash was load->drain->compute (vmcnt(0)
// at the second __syncthreads every K-tile => staging latency fully exposed;
// counters: 38% no-issue cycles, MfmaUtil 17.7, VALUBusy 44, HBM 12.7%).
// New schedule (T14/T3-minimum from learn_hip, +17% measured on attn):
//   barrier; issue V(t)->Vs, mask->regs, K(t+1)->Ks[cur^1];
//   vmcnt(8) [drains K(t), issued one full iter earlier]; barrier; QK^T;
//   vmcnt(2) [drains V(t)+mask, K(t+1) stays in flight]; softmax->Ps;
//   barrier; PV. s_setprio(1) around both MFMA clusters.
// K double-buffered (LDS 33.8KB, still 4 blocks/CU); V single (dbuf V would
// drop to 3 blocks/CU -> 25% tail on the 1024-block grid). Mask via per-lane
// int4 register loads (uniform vmcnt ledger, no divergent LDS path).
// gemm_qkv / gemm_out / prepasses unchanged from R11 to isolate the delta.
// ws >= 32MB: bf16 k,q,v + 4 transposed bf16 weights. Intermediates in dead
// fp32 input buffers. XOR-swizzled LDS everywhere (conflict-free + DMA-legal).

typedef __bf16 bf16;
typedef __bf16 bf16x8 __attribute__((ext_vector_type(8)));
typedef __bf16 bf16x4 __attribute__((ext_vector_type(4)));
typedef float f32x4 __attribute__((ext_vector_type(4)));

#define MFMA16(a, b, c) __builtin_amdgcn_mfma_f32_16x16x32_bf16((a), (b), (c), 0, 0, 0)

__device__ __forceinline__ void load_lds16(const bf16* g, bf16* l) {
  __builtin_amdgcn_global_load_lds(
      (const __attribute__((address_space(1))) unsigned int*)g,
      (__attribute__((address_space(3))) unsigned int*)l, 16, 0, 0);
}

__device__ __forceinline__ bf16x8 cvt8(const float* __restrict__ p) {
  const f32x4 a = *(const f32x4*)p;
  const f32x4 b = *(const f32x4*)(p + 4);
  bf16x8 r;
  r[0] = (bf16)a[0]; r[1] = (bf16)a[1]; r[2] = (bf16)a[2]; r[3] = (bf16)a[3];
  r[4] = (bf16)b[0]; r[5] = (bf16)b[1]; r[6] = (bf16)b[2]; r[7] = (bf16)b[3];
  return r;
}

// ---------------------------------------------------------------------------
// Prepass 1: k,q,v (4M fp32 each) -> bf16.
// ---------------------------------------------------------------------------
__global__ __launch_bounds__(256) void convert3(const float* __restrict__ a,
                                                const float* __restrict__ b,
                                                const float* __restrict__ c,
                                                bf16* __restrict__ oa,
                                                bf16* __restrict__ ob,
                                                bf16* __restrict__ oc) {
  const size_t i = ((size_t)blockIdx.x * 256 + threadIdx.x) * 8;
  const int which = (int)(i >> 22);
  const size_t off = i & ((size_t)(1u << 22) - 1);
  const float* src = which == 0 ? a : (which == 1 ? b : c);
  bf16* dst = which == 0 ? oa : (which == 1 ? ob : oc);
  *(bf16x8*)&dst[off] = cvt8(&src[off]);
}

// ---------------------------------------------------------------------------
// Prepass 2: W [1024k x 1024n] fp32 -> WT [n][k] bf16. grid (16,16,4).
// ---------------------------------------------------------------------------
__global__ __launch_bounds__(256) void transposeW(
    const float* __restrict__ W0, const float* __restrict__ W1,
    const float* __restrict__ W2, const float* __restrict__ W3,
    bf16* __restrict__ T0, bf16* __restrict__ T1, bf16* __restrict__ T2,
    bf16* __restrict__ T3) {
  __shared__ bf16 t[64 * 72];
  const int z = blockIdx.z;
  const float* W = z == 0 ? W0 : (z == 1 ? W1 : (z == 2 ? W2 : W3));
  bf16* T = z == 0 ? T0 : (z == 1 ? T1 : (z == 2 ? T2 : T3));
  const int kBase = blockIdx.y * 64, nBase = blockIdx.x * 64;
  const int tid = threadIdx.x;
  const int row = tid >> 2, cs = (tid & 3) * 16;

  const float* src = &W[(size_t)(kBase + row) * 1024 + nBase + cs];
  *(bf16x8*)&t[row * 72 + cs] = cvt8(src);
  *(bf16x8*)&t[row * 72 + cs + 8] = cvt8(src + 8);
  __syncthreads();

  const int n = tid >> 2, ks = (tid & 3) * 16;
  bf16 buf[16];
#pragma unroll
  for (int j = 0; j < 16; ++j) buf[j] = t[(ks + j) * 72 + n];
  bf16* dst = &T[(size_t)(nBase + n) * 1024 + kBase + ks];
  *(bf16x8*)&dst[0] = *(bf16x8*)&buf[0];
  *(bf16x8*)&dst[8] = *(bf16x8*)&buf[8];
}

// ---------------------------------------------------------------------------
// gemm_qkv: fused K/V/Q projections. BM=128, BN=64 (one head per block),
// BK=64; 4 waves, wave tile 64x32 (4x2 acc, 16 MFMA/iter); 24KB LDS ->
// 6 blocks/CU; grid (16,32,3) = 1536 blocks.
// z=0: K (bh,t,d). z=1: Vt (bh,d,t) via LDS transpose. z=2: Q, *0.125.
// ---------------------------------------------------------------------------
__global__ __launch_bounds__(256) void gemm_qkv(
    const bf16* __restrict__ kb, const bf16* __restrict__ vb,
    const bf16* __restrict__ qb, const bf16* __restrict__ WkT,
    const bf16* __restrict__ WvT, const bf16* __restrict__ WqT,
    const float* __restrict__ bk, const float* __restrict__ bv,
    const float* __restrict__ bq, bf16* __restrict__ K_buf,
    bf16* __restrict__ Vt_buf, bf16* __restrict__ Q_buf) {
  // S: As = [0, 8192) [m][k], Ws = [8192, 12288) [n][k]. 24 KB.
  __shared__ __align__(16) bf16 S[12288];
  bf16* As = S;
  bf16* Ws = S + 8192;
  const int tid = threadIdx.x;
  const int lane = tid & 63, w = tid >> 6;
  const int l15 = lane & 15, quad = lane >> 4;
  const int z = blockIdx.z;
  const bf16* X = z == 0 ? kb : (z == 1 ? vb : qb);
  const bf16* WT = z == 0 ? WkT : (z == 1 ? WvT : WqT);
  const float* B = z == 0 ? bk : (z == 1 ? bv : bq);
  const int mBase = blockIdx.y * 128, nBase = blockIdx.x * 64;
  const int wm = (w >> 1) * 64, wn = (w & 1) * 32;

  const int r8 = tid >> 3;                    // 0..31
  const int jg = ((tid & 7) ^ (r8 & 7)) * 8;  // swizzled col seg
  const int sw = l15 & 7;

  f32x4 acc[4][2] = {};

  for (int k0 = 0; k0 < 1024; k0 += 64) {
    __syncthreads();
#pragma unroll
    for (int i = 0; i < 4; ++i)
      load_lds16(&X[(size_t)(mBase + r8 + i * 32) * 1024 + k0 + jg],
                 &As[(tid + i * 256) * 8]);
#pragma unroll
    for (int i = 0; i < 2; ++i)
      load_lds16(&WT[(size_t)(nBase + r8 + i * 32) * 1024 + k0 + jg],
                 &Ws[(tid + i * 256) * 8]);
    __syncthreads();

#pragma unroll
    for (int k2 = 0; k2 < 2; ++k2) {
      const int col = ((k2 * 4 + quad) ^ sw) * 8;
      bf16x8 a[4], bb[2];
#pragma unroll
      for (int mt = 0; mt < 4; ++mt)
        a[mt] = *(const bf16x8*)&As[(wm + mt * 16 + l15) * 64 + col];
#pragma unroll
      for (int nt = 0; nt < 2; ++nt)
        bb[nt] = *(const bf16x8*)&Ws[(wn + nt * 16 + l15) * 64 + col];
#pragma unroll
      for (int mt = 0; mt < 4; ++mt)
#pragma unroll
        for (int nt = 0; nt < 2; ++nt)
          acc[mt][nt] = MFMA16(a[mt], bb[nt], acc[mt][nt]);
    }
  }

  // Epilogue. C layout: col = l15 (n-local), row = quad*4+r (m-local).
  const int h = nBase >> 6;  // BN=64: one head per block
  if (z != 1) {
    const float scale = (z == 2) ? 0.125f : 1.0f;
    bf16* o = (z == 0) ? K_buf : Q_buf;
#pragma unroll
    for (int nt = 0; nt < 2; ++nt) {
      const int n = nBase + wn + nt * 16 + l15;
      const float bias = B[n];
      const int d = n & 63;
#pragma unroll
      for (int mt = 0; mt < 4; ++mt)
#pragma unroll
        for (int r = 0; r < 4; ++r) {
          const int m = mBase + wm + mt * 16 + quad * 4 + r;
          const int b = m >> 11, t = m & 2047;
          o[((size_t)(b * 16 + h) * 2048 + t) * 64 + d] =
              (bf16)((acc[mt][nt][r] + bias) * scale);
        }
    }
  } else {
    // Vt: transpose each wave's 64(t)x32(d) C-tile in LDS, store b128 along t.
    __syncthreads();  // frag reads of S done
    bf16* Tb = &S[w * 2304];  // 32 x 72
#pragma unroll
    for (int nt = 0; nt < 2; ++nt) {
      const int n = nBase + wn + nt * 16 + l15;
      const float bias = B[n];
#pragma unroll
      for (int mt = 0; mt < 4; ++mt) {
        bf16x4 pk;
#pragma unroll
        for (int r = 0; r < 4; ++r) pk[r] = (bf16)(acc[mt][nt][r] + bias);
        *(bf16x4*)&Tb[(nt * 16 + l15) * 72 + mt * 16 + quad * 4] = pk;
      }
    }
    // same-wave in-order LDS: no barrier needed
    const int b = mBase >> 11;  // 128-row tile never straddles batch
#pragma unroll
    for (int i = 0; i < 4; ++i) {
      const int dl = i * 8 + (lane >> 3), ts = (lane & 7) * 8;
      const bf16x8 vv = *(const bf16x8*)&Tb[dl * 72 + ts];
      const int d = wn + dl;
      const int t = (mBase + wm + ts) & 2047;
      *(bf16x8*)&Vt_buf[((size_t)(b * 16 + h) * 64 + d) * 2048 + t] = vv;
    }
  }
}

// ---------------------------------------------------------------------------
// gemm_out (R9 exact): out = A @ WoT^T + bo -> fp32. BM=128, BN=64, BK=64.
// ---------------------------------------------------------------------------
__global__ __launch_bounds__(256) void gemm_out(const bf16* __restrict__ X,
                                                const bf16* __restrict__ WT,
                                                const float* __restrict__ B,
                                                float* __restrict__ out) {
  __shared__ __align__(16) bf16 As[128 * 64];
  __shared__ __align__(16) bf16 Ws[64 * 64];
  const int tid = threadIdx.x;
  const int lane = tid & 63, w = tid >> 6;
  const int l15 = lane & 15, quad = lane >> 4;
  const int mBase = blockIdx.y * 128, nBase = blockIdx.x * 64;
  const int wm = (w >> 1) * 64, wn = (w & 1) * 32;

  const int r8 = tid >> 3;
  const int jg = ((tid & 7) ^ (r8 & 7)) * 8;
  const int sw = l15 & 7;

  f32x4 acc[4][2] = {};

  for (int k0 = 0; k0 < 1024; k0 += 64) {
    __syncthreads();
#pragma unroll
    for (int i = 0; i < 4; ++i)
      load_lds16(&X[(size_t)(mBase + r8 + i * 32) * 1024 + k0 + jg],
                 &As[(tid + i * 256) * 8]);
#pragma unroll
    for (int i = 0; i < 2; ++i)
      load_lds16(&WT[(size_t)(nBase + r8 + i * 32) * 1024 + k0 + jg],
                 &Ws[(tid + i * 256) * 8]);
    __syncthreads();

#pragma unroll
    for (int k2 = 0; k2 < 2; ++k2) {
      const int col = ((k2 * 4 + quad) ^ sw) * 8;
      bf16x8 a[4], bb[2];
#pragma unroll
      for (int mt = 0; mt < 4; ++mt)
        a[mt] = *(const bf16x8*)&As[(wm + mt * 16 + l15) * 64 + col];
#pragma unroll
      for (int nt = 0; nt < 2; ++nt)
        bb[nt] = *(const bf16x8*)&Ws[(wn + nt * 16 + l15) * 64 + col];
#pragma unroll
      for (int mt = 0; mt < 4; ++mt)
#pragma unroll
        for (int nt = 0; nt < 2; ++nt)
          acc[mt][nt] = MFMA16(a[mt], bb[nt], acc[mt][nt]);
    }
  }

#pragma unroll
  for (int nt = 0; nt < 2; ++nt) {
    const int n = nBase + wn + nt * 16 + l15;
    const float bias = B[n];
#pragma unroll
    for (int mt = 0; mt < 4; ++mt)
#pragma unroll
      for (int r = 0; r < 4; ++r) {
        const int m = mBase + wm + mt * 16 + quad * 4 + r;
        out[(size_t)m * 1024 + n] = acc[mt][nt][r] + bias;
      }
  }
}

// ---------------------------------------------------------------------------
// flash_attn (R12): S^T/O^T form, fixed-reference softmax (m=0), per-lane
// scalar row sum. Pipelined: K double-buffered via global_load_lds, counted
// vmcnt (never 0 in the loop), raw s_barrier, setprio around MFMA clusters.
// vmcnt ledger per iter (issue order): V(t) x2, mask(t) x4, K(t+1) x2.
//   - vmcnt(8) before QK  -> drains K(t)   (issued one iter earlier: free)
//   - vmcnt(2) before SM  -> drains V(t)+M(t), K(t+1) stays in flight
// ---------------------------------------------------------------------------
__global__ __launch_bounds__(256) void flash_attn(const bf16* __restrict__ Q,
                                                  const bf16* __restrict__ K,
                                                  const bf16* __restrict__ Vt,
                                                  const int* __restrict__ mask,
                                                  bf16* __restrict__ A) {
  __shared__ __align__(16) bf16 Ks[2][64 * 64];  // [key][d] swizzled, dbuf
  __shared__ __align__(16) bf16 Vs[64 * 64];     // [d][key] swizzled
  __shared__ __align__(16) bf16 Ps[64 * 72];     // [q][key], wave-private rows

  const int tid = threadIdx.x;
  const int lane = tid & 63, w = tid >> 6;
  const int l15 = lane & 15, quad = lane >> 4;
  const int bh = blockIdx.y;
  const int b = bh >> 4, h = bh & 15;
  const int qt = blockIdx.x * 64;

  const int r8 = tid >> 3;
  const int jg = ((tid & 7) ^ (r8 & 7)) * 8;
  const int sw = l15 & 7;

  const size_t qbase = ((size_t)bh * 2048 + qt + w * 16 + l15) * 64;
  const bf16x8 bq0 = *(const bf16x8*)&Q[qbase + quad * 8];
  const bf16x8 bq1 = *(const bf16x8*)&Q[qbase + 32 + quad * 8];

  const int* __restrict__ mrow = &mask[b * 2048];

  f32x4 o[4] = {};
  float rs = 0.0f;

  // Prologue: K(0) -> Ks[0]. Outstanding: 2 (matches steady state).
#pragma unroll
  for (int i = 0; i < 2; ++i)
    load_lds16(&K[((size_t)bh * 2048 + r8 + i * 32) * 64 + jg],
               &Ks[0][(tid + i * 256) * 8]);

  int cur = 0;
  for (int kt = 0; kt < 2048; kt += 64) {
    // barrier[1]: PV(t-1) done everywhere -> Vs free; QK(t-1) done -> Ks[cur^1] free.
    __builtin_amdgcn_s_barrier();

    // Issue V(t) -> Vs (vmcnt +2)
#pragma unroll
    for (int i = 0; i < 2; ++i)
      load_lds16(&Vt[((size_t)bh * 64 + r8 + i * 32) * 2048 + kt + jg],
                 &Vs[(tid + i * 256) * 8]);
    // Issue mask(t) -> regs (vmcnt +4)
    int4 mi[4];
#pragma unroll
    for (int nt = 0; nt < 4; ++nt)
      mi[nt] = *(const int4*)&mrow[kt + nt * 16 + quad * 4];
    // Issue K(t+1) -> Ks[cur^1] (vmcnt +2). Last iter wraps to tile 0 into the
    // dead buffer: keeps the vmcnt ledger uniform, never read.
    const int ktn = (kt + 64) & 2047;
#pragma unroll
    for (int i = 0; i < 2; ++i)
      load_lds16(&K[((size_t)bh * 2048 + ktn + r8 + i * 32) * 64 + jg],
                 &Ks[cur ^ 1][(tid + i * 256) * 8]);

    // K(t) arrived (8 newer ops outstanding); make it visible block-wide.
    asm volatile("s_waitcnt vmcnt(8)" ::: "memory");
    __builtin_amdgcn_s_barrier();  // barrier[2]

    // QK^T on Ks[cur]
    const bf16* Kc = Ks[cur];
    f32x4 s4[4];
    __builtin_amdgcn_s_setprio(1);
#pragma unroll
    for (int nt = 0; nt < 4; ++nt) {
      const bf16x8 ak0 = *(const bf16x8*)&Kc[(nt * 16 + l15) * 64 + ((quad ^ sw) * 8)];
      const bf16x8 ak1 = *(const bf16x8*)&Kc[(nt * 16 + l15) * 64 + (((4 + quad) ^ sw) * 8)];
      f32x4 s = {};
      s = MFMA16(ak0, bq0, s);
      s = MFMA16(ak1, bq1, s);
      s4[nt] = s;
    }
    __builtin_amdgcn_s_setprio(0);

    // V(t) + mask(t) arrived; K(t+1) stays in flight across the next barrier.
    asm volatile("s_waitcnt vmcnt(2)" ::: "memory");

    // Softmax -> Ps (rows wave-private, DS in-order per wave: no barrier).
#pragma unroll
    for (int nt = 0; nt < 4; ++nt) {
      const float p0 = mi[nt].x ? __expf(s4[nt][0]) : 0.0f;
      const float p1 = mi[nt].y ? __expf(s4[nt][1]) : 0.0f;
      const float p2 = mi[nt].z ? __expf(s4[nt][2]) : 0.0f;
      const float p3 = mi[nt].w ? __expf(s4[nt][3]) : 0.0f;
      rs += (p0 + p1) + (p2 + p3);
      bf16x4 pk;
      pk[0] = (bf16)p0; pk[1] = (bf16)p1; pk[2] = (bf16)p2; pk[3] = (bf16)p3;
      *(bf16x4*)&Ps[(w * 16 + l15) * 72 + nt * 16 + quad * 4] = pk;
    }

    __builtin_amdgcn_s_barrier();  // barrier[3]: everyone's V(t) drained -> Vs visible

    __builtin_amdgcn_s_setprio(1);
#pragma unroll
    for (int ks = 0; ks < 2; ++ks) {
      const bf16x8 bp = *(const bf16x8*)&Ps[(w * 16 + l15) * 72 + ks * 32 + quad * 8];
#pragma unroll
      for (int mt = 0; mt < 4; ++mt) {
        const bf16x8 av =
            *(const bf16x8*)&Vs[(mt * 16 + l15) * 64 + (((ks * 4 + quad) ^ sw) * 8)];
        o[mt] = MFMA16(av, bp, o[mt]);
      }
    }
    __builtin_amdgcn_s_setprio(0);

    cur ^= 1;
  }

  rs += __shfl_xor(rs, 16);
  rs += __shfl_xor(rs, 32);
  const float inv = rs > 0.0f ? 1.0f / rs : 0.0f;

  const int t = qt + w * 16 + l15;
  const size_t base = ((size_t)b * 2048 + t) * 1024 + h * 64;
#pragma unroll
  for (int mt = 0; mt < 4; ++mt) {
    bf16x4 ov;
#pragma unroll
    for (int r = 0; r < 4; ++r) ov[r] = (bf16)(o[mt][r] * inv);
    *(bf16x4*)&A[base + mt * 16 + quad * 4] = ov;
  }
}

// ---------------------------------------------------------------------------
extern "C" void kernel_launch(void* const* d_in, const int* in_sizes, int n_in,
                              void* d_out, int out_size, void* d_ws, size_t ws_size,
                              hipStream_t stream) {
  const float* k = (const float*)d_in[0];
  const float* q = (const float*)d_in[1];
  const float* v = (const float*)d_in[2];
  const int* mask = (const int*)d_in[3];
  const float* Wk = (const float*)d_in[4];
  const float* bk = (const float*)d_in[5];
  const float* Wq = (const float*)d_in[6];
  const float* bq = (const float*)d_in[7];
  const float* Wv = (const float*)d_in[8];
  const float* bv = (const float*)d_in[9];
  const float* Wo = (const float*)d_in[10];
  const float* bo = (const float*)d_in[11];

  const size_t ELEMS = (size_t)4 * 1024 * 1024;
  const size_t WELEMS = (size_t)1024 * 1024;

  bf16* kb = (bf16*)d_ws;
  bf16* qb = kb + ELEMS;
  bf16* vb = qb + ELEMS;
  bf16* WkT = vb + ELEMS;
  bf16* WqT = WkT + WELEMS;
  bf16* WvT = WqT + WELEMS;
  bf16* WoT = WvT + WELEMS;

  bf16* K_buf = (bf16*)d_in[0];
  bf16* Q_buf = (bf16*)d_in[0] + ELEMS;
  bf16* Vt_buf = (bf16*)d_in[2];
  bf16* A_buf = (bf16*)d_in[2] + ELEMS;

  convert3<<<6144, 256, 0, stream>>>(k, q, v, kb, qb, vb);
  transposeW<<<dim3(16, 16, 4), 256, 0, stream>>>(Wk, Wq, Wv, Wo,
                                                  WkT, WqT, WvT, WoT);
  gemm_qkv<<<dim3(16, 32, 3), 256, 0, stream>>>(kb, vb, qb, WkT, WvT, WqT,
                                                bk, bv, bq, K_buf, Vt_buf, Q_buf);
  flash_attn<<<dim3(32, 32), 256, 0, stream>>>(Q_buf, K_buf, Vt_buf, mask, A_buf);
  gemm_out<<<dim3(16, 32), 256, 0, stream>>>(A_buf, WoT, bo, (float*)d_out);
}